// Round 10
// baseline (72.812 us; speedup 1.0000x reference)
//
#include <hip/hip_runtime.h>
#include <hip/hip_bf16.h>

// Problem constants (B,T,D,F) = (4,1024,256,128)
#define BT 4096
#define DD 256
#define CAT 129

typedef __attribute__((ext_vector_type(8))) _Float16 f16x8;
typedef __attribute__((ext_vector_type(4))) _Float16 f16x4;
typedef __attribute__((ext_vector_type(2))) _Float16 h2;
typedef __attribute__((ext_vector_type(4))) float f32x4;

// Opacity pin: forbids rematerialization of loaded persistent state.
#define PIN(x) asm volatile("" : "+v"(x))

static __device__ __forceinline__ h2 cvt_pk(float a, float b) {
    return __builtin_bit_cast(h2, __builtin_amdgcn_cvt_pkrtz(a, b));
}

static __device__ __forceinline__ float fdot2f(h2 a, h2 b, float c) {
#if __has_builtin(__builtin_amdgcn_fdot2)
    return __builtin_amdgcn_fdot2(__builtin_bit_cast(__fp16 __attribute__((ext_vector_type(2))), a),
                                  __builtin_bit_cast(__fp16 __attribute__((ext_vector_type(2))), b),
                                  c, false);
#else
    return fmaf((float)a[0], (float)b[0], fmaf((float)a[1], (float)b[1], c));
#endif
}

// ---------------------------------------------------------------------------
// k_cvt: blocks 0..7: W2 -> f16 LINEAR. blocks 8..15: W1[:,1:] -> f16
// XOR-swizzled (for k_prep2); block 8 also emits w10h = W1[:,0] in f16.
// ---------------------------------------------------------------------------
__global__ void __launch_bounds__(256) k_cvt(
    const float* __restrict__ W1, const float* __restrict__ W2,
    _Float16* __restrict__ w2h, _Float16* __restrict__ w1h,
    _Float16* __restrict__ w10h)
{
    const int t = threadIdx.x, b = blockIdx.x;
    if (b < 8) {
        #pragma unroll
        for (int i = 0; i < 8; ++i) {
            int idx = b * 2048 + i * 256 + t;       // g*128+f, linear
            w2h[idx] = (_Float16)W2[idx];
        }
    } else {
        int q = b - 8;
        #pragma unroll
        for (int i = 0; i < 8; ++i) {
            int idx = q * 2048 + i * 256 + t;       // f*128+c
            int f = idx >> 7, c = idx & 127;
            w1h[idx ^ ((f & 7) << 3)] = (_Float16)W1[f * CAT + 1 + c];
        }
        if (q == 0 && t < 128) w10h[t] = (_Float16)W1[t * CAT];
    }
}

// ---------------------------------------------------------------------------
// k_prep2: v1 = b1 + feature @ W1[:,1:]^T  (f16 MFMA GEMM, 16 rows/block),
// output stored as f16, linear [bt][f].
// ---------------------------------------------------------------------------
__global__ void __launch_bounds__(256) k_prep2(
    const float* __restrict__ feature, const _Float16* __restrict__ w1h,
    const float* __restrict__ b1p, _Float16* __restrict__ v1h)
{
    __shared__ __align__(16) _Float16 fS[2048];   // 16 x 128 f16, swizzled
    const int t = threadIdx.x;
    const int r0 = blockIdx.x * 16;

    {
        int e = t * 8;
        int r = e >> 7, c = e & 127;
        const float4* src = (const float4*)(feature + (size_t)(r0 + r) * 128 + c);
        float4 x0 = src[0], x1 = src[1];
        f16x8 hv;
        hv[0] = (_Float16)x0.x; hv[1] = (_Float16)x0.y;
        hv[2] = (_Float16)x0.z; hv[3] = (_Float16)x0.w;
        hv[4] = (_Float16)x1.x; hv[5] = (_Float16)x1.y;
        hv[6] = (_Float16)x1.z; hv[7] = (_Float16)x1.w;
        *(f16x8*)&fS[e ^ ((r & 7) << 3)] = hv;
    }
    __syncthreads();

    const int lane = t & 63, wv = t >> 6;
    const int l15 = lane & 15, l4 = lane >> 4;

    f16x8 bfr[2][4];
    float4 b1v[2];
    #pragma unroll
    for (int nt = 0; nt < 2; ++nt) {
        const int f0 = wv * 32 + nt * 16;
        b1v[nt] = *(const float4*)(b1p + f0 + l4 * 4);
        #pragma unroll
        for (int kc = 0; kc < 4; ++kc) {
            int f = f0 + l15, c = kc * 32 + l4 * 8;
            bfr[nt][kc] = *(const f16x8*)&w1h[(f * 128 + c) ^ ((f & 7) << 3)];
        }
    }

    const f32x4 fz = {0.f, 0.f, 0.f, 0.f};
    f32x4 acc[2] = {fz, fz};
    #pragma unroll
    for (int kc = 0; kc < 4; ++kc) {
        int r = l15, c = kc * 32 + l4 * 8;
        f16x8 afr = *(const f16x8*)&fS[(r * 128 + c) ^ ((r & 7) << 3)];
        #pragma unroll
        for (int nt = 0; nt < 2; ++nt)
            acc[nt] = __builtin_amdgcn_mfma_f32_16x16x32_f16(
                bfr[nt][kc], afr, acc[nt], 0, 0, 0);
    }

    #pragma unroll
    for (int nt = 0; nt < 2; ++nt) {
        f16x4 o;
        o[0] = (_Float16)(acc[nt][0] + ((const float*)&b1v[nt])[0]);
        o[1] = (_Float16)(acc[nt][1] + ((const float*)&b1v[nt])[1]);
        o[2] = (_Float16)(acc[nt][2] + ((const float*)&b1v[nt])[2]);
        o[3] = (_Float16)(acc[nt][3] + ((const float*)&b1v[nt])[3]);
        *(f16x4*)&v1h[(size_t)(r0 + l15) * 128 + wv * 32 + nt * 16 + l4 * 4] = o;
    }
}

// ---------------------------------------------------------------------------
// k_main: BARRIER-FREE, LDS-FREE, occupancy-first. 16384 independent waves;
// wave W = (bt = W>>2, cg = W&3): 16 iters of 16 rows x 32 g-cols.
// Persistent state is only ~88 regs (bfr[2][4]=32, v1/w10 windows 32,
// Wp packed 8, b2 C-init 8), pinned; __launch_bounds__(256,4) caps total
// V+A at 128 -> 4 waves/SIMD resident (fixes r8/r9's 2/SIMD at ~190 regs).
// Per iter: in-reg h1 B-frag gen -> 8 MFMA -> packed epilogue -> 2-shfl
// reduce -> one u32 packed-f16 partial store into plane pr[cg].
// ---------------------------------------------------------------------------
__global__ void __launch_bounds__(256, 4) k_main(
    const float* __restrict__ inp, const float* __restrict__ b2p,
    const float* __restrict__ Wp, const float* __restrict__ a1p,
    const float* __restrict__ a2p, const _Float16* __restrict__ v1h,
    const _Float16* __restrict__ w2h, const _Float16* __restrict__ w10h,
    unsigned* __restrict__ pr)
{
    const int tid  = threadIdx.x;
    const int lane = tid & 63, wv = tid >> 6;
    const int l15  = lane & 15, l4 = lane >> 4;
    const int W    = blockIdx.x * 4 + wv;     // 0..16383
    const int cg   = W & 3, bt = W >> 2;

    // ---- persistent W2 fragments: g = cg*32 + nt*16 + l15, f-window l4 ----
    f16x8 bfr[2][4];
    #pragma unroll
    for (int nt = 0; nt < 2; ++nt)
        #pragma unroll
        for (int kc = 0; kc < 4; ++kc) {
            bfr[nt][kc] = *(const f16x8*)
                &w2h[(cg * 32 + nt * 16 + l15) * 128 + kc * 32 + l4 * 8];
            PIN(bfr[nt][kc]);
        }

    // ---- v1 / w10 lane-windows (f = kc*32 + l4*8 .. +8) ----
    f16x8 v1pk[4], w10pk[4];
    #pragma unroll
    for (int kc = 0; kc < 4; ++kc) {
        v1pk[kc]  = *(const f16x8*)&v1h[(size_t)bt * 128 + kc * 32 + l4 * 8];
        w10pk[kc] = *(const f16x8*)&w10h[kc * 32 + l4 * 8];
        PIN(v1pk[kc]); PIN(w10pk[kc]);
    }

    // ---- b2 as f32 MFMA C-init + packed Wp slices ----
    f32x4 accInit[2];
    h2 wpapk[2][2], wpbpk[2][2];
    #pragma unroll
    for (int nt = 0; nt < 2; ++nt) {
        const int g0 = cg * 32 + nt * 16 + l4 * 4;
        const float4 bv = *(const float4*)&b2p[g0];
        const float4 wa = *(const float4*)&Wp[g0];
        accInit[nt][0] = bv.x; accInit[nt][1] = bv.y;
        accInit[nt][2] = bv.z; accInit[nt][3] = bv.w;
        wpapk[nt][0] = cvt_pk(wa.x, wa.y);  wpapk[nt][1] = cvt_pk(wa.z, wa.w);
        wpbpk[nt][0] = cvt_pk(Wp[CAT + g0],     Wp[CAT + g0 + 1]);
        wpbpk[nt][1] = cvt_pk(Wp[CAT + g0 + 2], Wp[CAT + g0 + 3]);
        PIN(accInit[nt]);
        PIN(wpapk[nt][0]); PIN(wpapk[nt][1]);
        PIN(wpbpk[nt][0]); PIN(wpbpk[nt][1]);
    }

    const _Float16 a1s = (_Float16)a1p[0];
    const _Float16 a2s = (_Float16)a2p[0];
    f16x8 a1x8 = {a1s, a1s, a1s, a1s, a1s, a1s, a1s, a1s};
    h2 a2v; a2v[0] = a2s; a2v[1] = a2s;
    PIN(a1x8); PIN(a2v);

    const float* srow = inp + (size_t)bt * DD;
    unsigned* prw = pr + (size_t)cg * (BT * DD) + (size_t)bt * DD;
    float s_cur = srow[l15];

    #pragma unroll 2
    for (int it = 0; it < 16; ++it) {
        const float s_row = s_cur;
        if (it < 15) s_cur = srow[(it + 1) * 16 + l15];   // prefetch next

        // ---- h1 B-fragments generated in registers ----
        const _Float16 sh = (_Float16)s_row;
        const f16x8 s8 = {sh, sh, sh, sh, sh, sh, sh, sh};

        f32x4 acc[2];
        #pragma unroll
        for (int kc = 0; kc < 4; ++kc) {
            f16x8 h  = v1pk[kc] + w10pk[kc] * s8;
            f16x8 af = __builtin_elementwise_max(h, a1x8 * h);   // prelu, a1 in [0,1]
            #pragma unroll
            for (int nt = 0; nt < 2; ++nt)
                acc[nt] = __builtin_amdgcn_mfma_f32_16x16x32_f16(
                    bfr[nt][kc], af, (kc == 0) ? accInit[nt] : acc[nt], 0, 0, 0);
        }

        // ---- packed epilogue: prelu(a2), Wp dots (b2 already in acc) ----
        float p0 = 0.f, p1 = 0.f;
        #pragma unroll
        for (int nt = 0; nt < 2; ++nt) {
            h2 hh0 = cvt_pk(acc[nt][0], acc[nt][1]);
            h2 hh1 = cvt_pk(acc[nt][2], acc[nt][3]);
            h2 hp0 = __builtin_elementwise_max(hh0, a2v * hh0);
            h2 hp1 = __builtin_elementwise_max(hh1, a2v * hh1);
            p0 = fdot2f(wpapk[nt][0], hp0, p0);
            p0 = fdot2f(wpapk[nt][1], hp1, p0);
            p1 = fdot2f(wpbpk[nt][0], hp0, p1);
            p1 = fdot2f(wpbpk[nt][1], hp1, p1);
        }

        // ---- in-wave reduce over l4 (4 lanes, stride 16) ----
        p0 += __shfl_xor(p0, 16); p0 += __shfl_xor(p0, 32);
        p1 += __shfl_xor(p1, 16); p1 += __shfl_xor(p1, 32);

        if (l4 == 0)   // coalesced: 16 lanes write 16 consecutive u32
            prw[it * 16 + l15] = __builtin_bit_cast(unsigned, cvt_pk(p0, p1));
    }
}

// ---------------------------------------------------------------------------
// k_fin: sum 4 cg planes + wpi*s + bp, sigmoid gate, write out. BW-bound.
// ---------------------------------------------------------------------------
__global__ void __launch_bounds__(256) k_fin(
    const float* __restrict__ inp, const float* __restrict__ Wp,
    const float* __restrict__ bpp, const unsigned* __restrict__ pr,
    float* __restrict__ out)
{
    const int i = blockIdx.x * 256 + threadIdx.x;   // 0 .. BT*DD-1
    const float wpi0 = Wp[128], wpi1 = Wp[CAT + 128];
    const float bp0  = bpp[0],  bp1  = bpp[1];

    const h2 pa = __builtin_bit_cast(h2, pr[i]);
    const h2 pb = __builtin_bit_cast(h2, pr[BT * DD + i]);
    const h2 pc = __builtin_bit_cast(h2, pr[2 * BT * DD + i]);
    const h2 pd = __builtin_bit_cast(h2, pr[3 * BT * DD + i]);
    const float s = inp[i];

    const float e0 = (float)pa[0] + (float)pb[0] + (float)pc[0] + (float)pd[0]
                   + wpi0 * s + bp0;
    const float e1 = (float)pa[1] + (float)pb[1] + (float)pc[1] + (float)pd[1]
                   + wpi1 * s + bp1;
    const float gg = e0 / (1.f + __expf(-e1));
    out[i] = s * (1.f + gg);
}

// ---------------------------------------------------------------------------
extern "C" void kernel_launch(void* const* d_in, const int* in_sizes, int n_in,
                              void* d_out, int out_size, void* d_ws, size_t ws_size,
                              hipStream_t stream)
{
    (void)in_sizes; (void)n_in; (void)out_size; (void)ws_size;
    const float* input   = (const float*)d_in[0];
    const float* feature = (const float*)d_in[1];
    // d_in[2] slider: unused by the reference computation
    const float* W1 = (const float*)d_in[3];
    const float* b1 = (const float*)d_in[4];
    const float* a1 = (const float*)d_in[5];
    const float* W2 = (const float*)d_in[6];
    const float* b2 = (const float*)d_in[7];
    const float* a2 = (const float*)d_in[8];
    const float* Wp = (const float*)d_in[9];
    const float* bp = (const float*)d_in[10];
    float* out = (float*)d_out;

    // workspace: pr 16MB (4 planes) | v1h 1MB | w2h 32KB | w1h 32KB | w10h 256B
    unsigned*  pr   = (unsigned*)d_ws;
    _Float16*  v1h  = (_Float16*)((char*)d_ws + (size_t)4 * BT * DD * 4);
    _Float16*  w2h  = v1h + (size_t)BT * 128;
    _Float16*  w1h  = w2h + 16384;
    _Float16*  w10h = w1h + 16384;

    k_cvt  <<<dim3(16),   dim3(256), 0, stream>>>(W1, W2, w2h, w1h, w10h);
    k_prep2<<<dim3(256),  dim3(256), 0, stream>>>(feature, w1h, b1, v1h);
    k_main <<<dim3(4096), dim3(256), 0, stream>>>(input, b2, Wp, a1, a2,
                                                  v1h, w2h, w10h, pr);
    k_fin  <<<dim3(4096), dim3(256), 0, stream>>>(input, Wp, bp, pr, out);
}

// Round 11
// 72.040 us; speedup vs baseline: 1.0107x; 1.0107x over previous
//
#include <hip/hip_runtime.h>
#include <hip/hip_bf16.h>

// Problem constants (B,T,D,F) = (4,1024,256,128)
#define BT 4096
#define DD 256
#define CAT 129

typedef __attribute__((ext_vector_type(8))) _Float16 f16x8;
typedef __attribute__((ext_vector_type(4))) _Float16 f16x4;
typedef __attribute__((ext_vector_type(2))) _Float16 h2;
typedef __attribute__((ext_vector_type(4))) float f32x4;

// Opacity pin: forbids rematerialization of loaded persistent state.
#define PIN(x) asm volatile("" : "+v"(x))

static __device__ __forceinline__ h2 cvt_pk(float a, float b) {
    return __builtin_bit_cast(h2, __builtin_amdgcn_cvt_pkrtz(a, b));
}

static __device__ __forceinline__ float fdot2f(h2 a, h2 b, float c) {
#if __has_builtin(__builtin_amdgcn_fdot2)
    return __builtin_amdgcn_fdot2(__builtin_bit_cast(__fp16 __attribute__((ext_vector_type(2))), a),
                                  __builtin_bit_cast(__fp16 __attribute__((ext_vector_type(2))), b),
                                  c, false);
#else
    return fmaf((float)a[0], (float)b[0], fmaf((float)a[1], (float)b[1], c));
#endif
}

// ---------------------------------------------------------------------------
// k_cvt: blocks 0..7: W2 -> f16 LINEAR. blocks 8..15: W1[:,1:] -> f16
// XOR-swizzled (for k_prep2); block 8 also emits w10h = W1[:,0] in f16.
// ---------------------------------------------------------------------------
__global__ void __launch_bounds__(256) k_cvt(
    const float* __restrict__ W1, const float* __restrict__ W2,
    _Float16* __restrict__ w2h, _Float16* __restrict__ w1h,
    _Float16* __restrict__ w10h)
{
    const int t = threadIdx.x, b = blockIdx.x;
    if (b < 8) {
        #pragma unroll
        for (int i = 0; i < 8; ++i) {
            int idx = b * 2048 + i * 256 + t;       // g*128+f, linear
            w2h[idx] = (_Float16)W2[idx];
        }
    } else {
        int q = b - 8;
        #pragma unroll
        for (int i = 0; i < 8; ++i) {
            int idx = q * 2048 + i * 256 + t;       // f*128+c
            int f = idx >> 7, c = idx & 127;
            w1h[idx ^ ((f & 7) << 3)] = (_Float16)W1[f * CAT + 1 + c];
        }
        if (q == 0 && t < 128) w10h[t] = (_Float16)W1[t * CAT];
    }
}

// ---------------------------------------------------------------------------
// k_prep2: v1 = b1 + feature @ W1[:,1:]^T  (f16 MFMA GEMM, 16 rows/block),
// output stored as f16, linear [bt][f].
// ---------------------------------------------------------------------------
__global__ void __launch_bounds__(256) k_prep2(
    const float* __restrict__ feature, const _Float16* __restrict__ w1h,
    const float* __restrict__ b1p, _Float16* __restrict__ v1h)
{
    __shared__ __align__(16) _Float16 fS[2048];   // 16 x 128 f16, swizzled
    const int t = threadIdx.x;
    const int r0 = blockIdx.x * 16;

    {
        int e = t * 8;
        int r = e >> 7, c = e & 127;
        const float4* src = (const float4*)(feature + (size_t)(r0 + r) * 128 + c);
        float4 x0 = src[0], x1 = src[1];
        f16x8 hv;
        hv[0] = (_Float16)x0.x; hv[1] = (_Float16)x0.y;
        hv[2] = (_Float16)x0.z; hv[3] = (_Float16)x0.w;
        hv[4] = (_Float16)x1.x; hv[5] = (_Float16)x1.y;
        hv[6] = (_Float16)x1.z; hv[7] = (_Float16)x1.w;
        *(f16x8*)&fS[e ^ ((r & 7) << 3)] = hv;
    }
    __syncthreads();

    const int lane = t & 63, wv = t >> 6;
    const int l15 = lane & 15, l4 = lane >> 4;

    f16x8 bfr[2][4];
    float4 b1v[2];
    #pragma unroll
    for (int nt = 0; nt < 2; ++nt) {
        const int f0 = wv * 32 + nt * 16;
        b1v[nt] = *(const float4*)(b1p + f0 + l4 * 4);
        #pragma unroll
        for (int kc = 0; kc < 4; ++kc) {
            int f = f0 + l15, c = kc * 32 + l4 * 8;
            bfr[nt][kc] = *(const f16x8*)&w1h[(f * 128 + c) ^ ((f & 7) << 3)];
        }
    }

    const f32x4 fz = {0.f, 0.f, 0.f, 0.f};
    f32x4 acc[2] = {fz, fz};
    #pragma unroll
    for (int kc = 0; kc < 4; ++kc) {
        int r = l15, c = kc * 32 + l4 * 8;
        f16x8 afr = *(const f16x8*)&fS[(r * 128 + c) ^ ((r & 7) << 3)];
        #pragma unroll
        for (int nt = 0; nt < 2; ++nt)
            acc[nt] = __builtin_amdgcn_mfma_f32_16x16x32_f16(
                bfr[nt][kc], afr, acc[nt], 0, 0, 0);
    }

    #pragma unroll
    for (int nt = 0; nt < 2; ++nt) {
        f16x4 o;
        o[0] = (_Float16)(acc[nt][0] + ((const float*)&b1v[nt])[0]);
        o[1] = (_Float16)(acc[nt][1] + ((const float*)&b1v[nt])[1]);
        o[2] = (_Float16)(acc[nt][2] + ((const float*)&b1v[nt])[2]);
        o[3] = (_Float16)(acc[nt][3] + ((const float*)&b1v[nt])[3]);
        *(f16x4*)&v1h[(size_t)(r0 + l15) * 128 + wv * 32 + nt * 16 + l4 * 4] = o;
    }
}

// ---------------------------------------------------------------------------
// k_main: barrier-free, LDS-free, DS-free (no shuffles). 8192 independent
// waves; wave W = (bt = W>>1, cg = W&1): 8 iters of 32 rows (2 independent
// row-streams) x 64 g-cols. Persistent: bfr[4][4]=64, v1/w10 windows 32,
// b2 C-init 16, packed Wp 16 (pinned). Per iter: 2x in-reg h1 frag-gen ->
// 8 independent 4-deep MFMA chains -> packed epilogue (split fdot2 chains)
// -> every lane stores its packed (p0,p1) f16 partial to plane pr[cg*4+l4].
// k_fin sums the 8 planes. __launch_bounds__(256,2): honest residency,
// no spill risk, full scheduling freedom.
// ---------------------------------------------------------------------------
__global__ void __launch_bounds__(256, 2) k_main(
    const float* __restrict__ inp, const float* __restrict__ b2p,
    const float* __restrict__ Wp, const float* __restrict__ a1p,
    const float* __restrict__ a2p, const _Float16* __restrict__ v1h,
    const _Float16* __restrict__ w2h, const _Float16* __restrict__ w10h,
    unsigned* __restrict__ pr)
{
    const int tid  = threadIdx.x;
    const int lane = tid & 63, wv = tid >> 6;
    const int l15  = lane & 15, l4 = lane >> 4;
    const int W    = blockIdx.x * 4 + wv;     // 0..8191
    const int cg   = W & 1, bt = W >> 1;

    // ---- persistent W2 fragments: g = cg*64 + nt*16 + l15, f-window l4 ----
    f16x8 bfr[4][4];
    #pragma unroll
    for (int nt = 0; nt < 4; ++nt)
        #pragma unroll
        for (int kc = 0; kc < 4; ++kc) {
            bfr[nt][kc] = *(const f16x8*)
                &w2h[(cg * 64 + nt * 16 + l15) * 128 + kc * 32 + l4 * 8];
            PIN(bfr[nt][kc]);
        }

    // ---- v1 / w10 lane-windows (f = kc*32 + l4*8 .. +8) ----
    f16x8 v1pk[4], w10pk[4];
    #pragma unroll
    for (int kc = 0; kc < 4; ++kc) {
        v1pk[kc]  = *(const f16x8*)&v1h[(size_t)bt * 128 + kc * 32 + l4 * 8];
        w10pk[kc] = *(const f16x8*)&w10h[kc * 32 + l4 * 8];
        PIN(v1pk[kc]); PIN(w10pk[kc]);
    }

    // ---- b2 as f32 MFMA C-init + packed Wp slices ----
    f32x4 accInit[4];
    h2 wpapk[4][2], wpbpk[4][2];
    #pragma unroll
    for (int nt = 0; nt < 4; ++nt) {
        const int g0 = cg * 64 + nt * 16 + l4 * 4;
        const float4 bv = *(const float4*)&b2p[g0];
        const float4 wa = *(const float4*)&Wp[g0];
        accInit[nt][0] = bv.x; accInit[nt][1] = bv.y;
        accInit[nt][2] = bv.z; accInit[nt][3] = bv.w;
        wpapk[nt][0] = cvt_pk(wa.x, wa.y);  wpapk[nt][1] = cvt_pk(wa.z, wa.w);
        wpbpk[nt][0] = cvt_pk(Wp[CAT + g0],     Wp[CAT + g0 + 1]);
        wpbpk[nt][1] = cvt_pk(Wp[CAT + g0 + 2], Wp[CAT + g0 + 3]);
        PIN(accInit[nt]);
        PIN(wpapk[nt][0]); PIN(wpapk[nt][1]);
        PIN(wpbpk[nt][0]); PIN(wpbpk[nt][1]);
    }

    const _Float16 a1s = (_Float16)a1p[0];
    const _Float16 a2s = (_Float16)a2p[0];
    const f16x8 a1x8 = {a1s, a1s, a1s, a1s, a1s, a1s, a1s, a1s};
    h2 a2v; a2v[0] = a2s; a2v[1] = a2s;

    const float* srow = inp + (size_t)bt * DD;
    unsigned* prw = pr + (size_t)(cg * 4 + l4) * (BT * DD) + (size_t)bt * DD;

    #pragma unroll 2
    for (int it = 0; it < 8; ++it) {
        // ---- two independent row-streams: rows it*32+l15 and +16 ----
        const float sAf = srow[it * 32 + l15];
        const float sBf = srow[it * 32 + 16 + l15];
        const _Float16 shA = (_Float16)sAf, shB = (_Float16)sBf;
        const f16x8 s8A = {shA, shA, shA, shA, shA, shA, shA, shA};
        const f16x8 s8B = {shB, shB, shB, shB, shB, shB, shB, shB};

        f32x4 accA[4], accB[4];
        #pragma unroll
        for (int kc = 0; kc < 4; ++kc) {
            f16x8 hA  = v1pk[kc] + w10pk[kc] * s8A;
            f16x8 afA = __builtin_elementwise_max(hA, a1x8 * hA);
            f16x8 hB  = v1pk[kc] + w10pk[kc] * s8B;
            f16x8 afB = __builtin_elementwise_max(hB, a1x8 * hB);
            #pragma unroll
            for (int nt = 0; nt < 4; ++nt) {
                accA[nt] = __builtin_amdgcn_mfma_f32_16x16x32_f16(
                    bfr[nt][kc], afA, (kc == 0) ? accInit[nt] : accA[nt], 0, 0, 0);
                accB[nt] = __builtin_amdgcn_mfma_f32_16x16x32_f16(
                    bfr[nt][kc], afB, (kc == 0) ? accInit[nt] : accB[nt], 0, 0, 0);
            }
        }

        // ---- packed epilogue; fdot2 chains split for ILP ----
        float p0Aa = 0.f, p0Ab = 0.f, p1Aa = 0.f, p1Ab = 0.f;
        float p0Ba = 0.f, p0Bb = 0.f, p1Ba = 0.f, p1Bb = 0.f;
        #pragma unroll
        for (int nt = 0; nt < 4; ++nt) {
            h2 hA0 = cvt_pk(accA[nt][0], accA[nt][1]);
            h2 hA1 = cvt_pk(accA[nt][2], accA[nt][3]);
            h2 pA0 = __builtin_elementwise_max(hA0, a2v * hA0);
            h2 pA1 = __builtin_elementwise_max(hA1, a2v * hA1);
            h2 hB0 = cvt_pk(accB[nt][0], accB[nt][1]);
            h2 hB1 = cvt_pk(accB[nt][2], accB[nt][3]);
            h2 pB0 = __builtin_elementwise_max(hB0, a2v * hB0);
            h2 pB1 = __builtin_elementwise_max(hB1, a2v * hB1);
            if (nt < 2) {
                p0Aa = fdot2f(wpapk[nt][0], pA0, p0Aa);
                p0Aa = fdot2f(wpapk[nt][1], pA1, p0Aa);
                p1Aa = fdot2f(wpbpk[nt][0], pA0, p1Aa);
                p1Aa = fdot2f(wpbpk[nt][1], pA1, p1Aa);
                p0Ba = fdot2f(wpapk[nt][0], pB0, p0Ba);
                p0Ba = fdot2f(wpapk[nt][1], pB1, p0Ba);
                p1Ba = fdot2f(wpbpk[nt][0], pB0, p1Ba);
                p1Ba = fdot2f(wpbpk[nt][1], pB1, p1Ba);
            } else {
                p0Ab = fdot2f(wpapk[nt][0], pA0, p0Ab);
                p0Ab = fdot2f(wpapk[nt][1], pA1, p0Ab);
                p1Ab = fdot2f(wpbpk[nt][0], pA0, p1Ab);
                p1Ab = fdot2f(wpbpk[nt][1], pA1, p1Ab);
                p0Bb = fdot2f(wpapk[nt][0], pB0, p0Bb);
                p0Bb = fdot2f(wpapk[nt][1], pB1, p0Bb);
                p1Bb = fdot2f(wpbpk[nt][0], pB0, p1Bb);
                p1Bb = fdot2f(wpbpk[nt][1], pB1, p1Bb);
            }
        }

        // ---- every lane stores its (p0,p1) partial; no shuffles ----
        prw[it * 32 + l15] =
            __builtin_bit_cast(unsigned, cvt_pk(p0Aa + p0Ab, p1Aa + p1Ab));
        prw[it * 32 + 16 + l15] =
            __builtin_bit_cast(unsigned, cvt_pk(p0Ba + p0Bb, p1Ba + p1Bb));
    }
}

// ---------------------------------------------------------------------------
// k_fin: sum 8 (cg,l4) planes + wpi*s + bp, sigmoid gate, write out.
// ---------------------------------------------------------------------------
__global__ void __launch_bounds__(256) k_fin(
    const float* __restrict__ inp, const float* __restrict__ Wp,
    const float* __restrict__ bpp, const unsigned* __restrict__ pr,
    float* __restrict__ out)
{
    const int i = blockIdx.x * 256 + threadIdx.x;   // 0 .. BT*DD-1
    const float wpi0 = Wp[128], wpi1 = Wp[CAT + 128];
    const float bp0  = bpp[0],  bp1  = bpp[1];

    float e0 = 0.f, e1 = 0.f;
    #pragma unroll
    for (int p = 0; p < 8; ++p) {
        const h2 v = __builtin_bit_cast(h2, pr[(size_t)p * (BT * DD) + i]);
        e0 += (float)v[0];
        e1 += (float)v[1];
    }
    const float s = inp[i];
    e0 += wpi0 * s + bp0;
    e1 += wpi1 * s + bp1;
    const float gg = e0 / (1.f + __expf(-e1));
    out[i] = s * (1.f + gg);
}

// ---------------------------------------------------------------------------
extern "C" void kernel_launch(void* const* d_in, const int* in_sizes, int n_in,
                              void* d_out, int out_size, void* d_ws, size_t ws_size,
                              hipStream_t stream)
{
    (void)in_sizes; (void)n_in; (void)out_size; (void)ws_size;
    const float* input   = (const float*)d_in[0];
    const float* feature = (const float*)d_in[1];
    // d_in[2] slider: unused by the reference computation
    const float* W1 = (const float*)d_in[3];
    const float* b1 = (const float*)d_in[4];
    const float* a1 = (const float*)d_in[5];
    const float* W2 = (const float*)d_in[6];
    const float* b2 = (const float*)d_in[7];
    const float* a2 = (const float*)d_in[8];
    const float* Wp = (const float*)d_in[9];
    const float* bp = (const float*)d_in[10];
    float* out = (float*)d_out;

    // workspace: pr 32MB (8 planes) | v1h 1MB | w2h 32KB | w1h 32KB | w10h 256B
    unsigned*  pr   = (unsigned*)d_ws;
    _Float16*  v1h  = (_Float16*)((char*)d_ws + (size_t)8 * BT * DD * 4);
    _Float16*  w2h  = v1h + (size_t)BT * 128;
    _Float16*  w1h  = w2h + 16384;
    _Float16*  w10h = w1h + 16384;

    k_cvt  <<<dim3(16),   dim3(256), 0, stream>>>(W1, W2, w2h, w1h, w10h);
    k_prep2<<<dim3(256),  dim3(256), 0, stream>>>(feature, w1h, b1, v1h);
    k_main <<<dim3(2048), dim3(256), 0, stream>>>(input, b2, Wp, a1, a2,
                                                  v1h, w2h, w10h, pr);
    k_fin  <<<dim3(4096), dim3(256), 0, stream>>>(input, Wp, bp, pr, out);
}

// Round 12
// 69.079 us; speedup vs baseline: 1.0540x; 1.0429x over previous
//
#include <hip/hip_runtime.h>
#include <hip/hip_bf16.h>

// Problem constants (B,T,D,F) = (4,1024,256,128)
#define BT 4096
#define DD 256
#define CAT 129

typedef __attribute__((ext_vector_type(8))) _Float16 f16x8;
typedef __attribute__((ext_vector_type(2))) _Float16 h2;
typedef __attribute__((ext_vector_type(2))) __fp16 fp16x2;
typedef __attribute__((ext_vector_type(4))) float f32x4;
typedef __attribute__((ext_vector_type(4))) unsigned u32x4;
typedef unsigned u32;

// Opacity pin: forbids rematerialization of loaded persistent state.
#define PIN(x) asm volatile("" : "+v"(x))

// Guaranteed-packed f16 math (VOP3P). Pure asm: schedulable, CSE-able.
static __device__ __forceinline__ u32 pk_fma(u32 a, u32 b, u32 c) {
    u32 d; asm("v_pk_fma_f16 %0, %1, %2, %3" : "=v"(d) : "v"(a), "v"(b), "v"(c));
    return d;
}
static __device__ __forceinline__ u32 pk_mul(u32 a, u32 b) {
    u32 d; asm("v_pk_mul_f16 %0, %1, %2" : "=v"(d) : "v"(a), "v"(b));
    return d;
}
static __device__ __forceinline__ u32 pk_max(u32 a, u32 b) {
    u32 d; asm("v_pk_max_f16 %0, %1, %2" : "=v"(d) : "v"(a), "v"(b));
    return d;
}

static __device__ __forceinline__ u32 cvtpk_u(float a, float b) {
    return __builtin_bit_cast(u32, __builtin_amdgcn_cvt_pkrtz(a, b));
}
static __device__ __forceinline__ h2 cvt_pk(float a, float b) {
    return __builtin_bit_cast(h2, __builtin_amdgcn_cvt_pkrtz(a, b));
}
static __device__ __forceinline__ float fdot2u(u32 a, u32 b, float c) {
#if __has_builtin(__builtin_amdgcn_fdot2)
    return __builtin_amdgcn_fdot2(__builtin_bit_cast(fp16x2, a),
                                  __builtin_bit_cast(fp16x2, b), c, false);
#else
    h2 x = __builtin_bit_cast(h2, a), y = __builtin_bit_cast(h2, b);
    return fmaf((float)x[0], (float)y[0], fmaf((float)x[1], (float)y[1], c));
#endif
}

// ---------------------------------------------------------------------------
// k_cvt: blocks 0..7: W2 -> f16 LINEAR. blocks 8..15: W1[:,1:] -> f16
// XOR-swizzled (for k_prep2); block 8 also emits w10h = W1[:,0] in f16.
// ---------------------------------------------------------------------------
__global__ void __launch_bounds__(256) k_cvt(
    const float* __restrict__ W1, const float* __restrict__ W2,
    _Float16* __restrict__ w2h, _Float16* __restrict__ w1h,
    _Float16* __restrict__ w10h)
{
    const int t = threadIdx.x, b = blockIdx.x;
    if (b < 8) {
        #pragma unroll
        for (int i = 0; i < 8; ++i) {
            int idx = b * 2048 + i * 256 + t;       // g*128+f, linear
            w2h[idx] = (_Float16)W2[idx];
        }
    } else {
        int q = b - 8;
        #pragma unroll
        for (int i = 0; i < 8; ++i) {
            int idx = q * 2048 + i * 256 + t;       // f*128+c
            int f = idx >> 7, c = idx & 127;
            w1h[idx ^ ((f & 7) << 3)] = (_Float16)W1[f * CAT + 1 + c];
        }
        if (q == 0 && t < 128) w10h[t] = (_Float16)W1[t * CAT];
    }
}

// ---------------------------------------------------------------------------
// k_prep2: v1 = b1 + feature @ W1[:,1:]^T  (f16 MFMA GEMM, 16 rows/block),
// output stored as f16, linear [bt][f].
// ---------------------------------------------------------------------------
__global__ void __launch_bounds__(256) k_prep2(
    const float* __restrict__ feature, const _Float16* __restrict__ w1h,
    const float* __restrict__ b1p, _Float16* __restrict__ v1h)
{
    __shared__ __align__(16) _Float16 fS[2048];   // 16 x 128 f16, swizzled
    const int t = threadIdx.x;
    const int r0 = blockIdx.x * 16;

    {
        int e = t * 8;
        int r = e >> 7, c = e & 127;
        const float4* src = (const float4*)(feature + (size_t)(r0 + r) * 128 + c);
        float4 x0 = src[0], x1 = src[1];
        f16x8 hv;
        hv[0] = (_Float16)x0.x; hv[1] = (_Float16)x0.y;
        hv[2] = (_Float16)x0.z; hv[3] = (_Float16)x0.w;
        hv[4] = (_Float16)x1.x; hv[5] = (_Float16)x1.y;
        hv[6] = (_Float16)x1.z; hv[7] = (_Float16)x1.w;
        *(f16x8*)&fS[e ^ ((r & 7) << 3)] = hv;
    }
    __syncthreads();

    const int lane = t & 63, wv = t >> 6;
    const int l15 = lane & 15, l4 = lane >> 4;

    f16x8 bfr[2][4];
    float4 b1v[2];
    #pragma unroll
    for (int nt = 0; nt < 2; ++nt) {
        const int f0 = wv * 32 + nt * 16;
        b1v[nt] = *(const float4*)(b1p + f0 + l4 * 4);
        #pragma unroll
        for (int kc = 0; kc < 4; ++kc) {
            int f = f0 + l15, c = kc * 32 + l4 * 8;
            bfr[nt][kc] = *(const f16x8*)&w1h[(f * 128 + c) ^ ((f & 7) << 3)];
        }
    }

    const f32x4 fz = {0.f, 0.f, 0.f, 0.f};
    f32x4 acc[2] = {fz, fz};
    #pragma unroll
    for (int kc = 0; kc < 4; ++kc) {
        int r = l15, c = kc * 32 + l4 * 8;
        f16x8 afr = *(const f16x8*)&fS[(r * 128 + c) ^ ((r & 7) << 3)];
        #pragma unroll
        for (int nt = 0; nt < 2; ++nt)
            acc[nt] = __builtin_amdgcn_mfma_f32_16x16x32_f16(
                bfr[nt][kc], afr, acc[nt], 0, 0, 0);
    }

    #pragma unroll
    for (int nt = 0; nt < 2; ++nt) {
        h2 o01 = cvt_pk(acc[nt][0] + ((const float*)&b1v[nt])[0],
                        acc[nt][1] + ((const float*)&b1v[nt])[1]);
        h2 o23 = cvt_pk(acc[nt][2] + ((const float*)&b1v[nt])[2],
                        acc[nt][3] + ((const float*)&b1v[nt])[3]);
        _Float16* dst = v1h + (size_t)(r0 + l15) * 128 + wv * 32 + nt * 16 + l4 * 4;
        *(h2*)dst = o01;
        *(h2*)(dst + 2) = o23;
    }
}

// ---------------------------------------------------------------------------
// k_main: barrier-free, LDS-free main loop with ZERO per-iter memory reads.
// 8192 independent waves; wave W = (bt = W>>1, cg = W&1): 8 iters of 32 rows
// (2 row-streams) x 64 g-cols. All f16 VALU is hand-packed (v_pk_* asm).
// All 16 s-values preloaded + pre-packed before the loop (PINned).
// Per iter: packed afr-gen -> 32 MFMA (b2 as C-init) -> packed epilogue ->
// 2-shfl l4-reduce -> 2 coalesced u32 partial stores. k_fin combines.
// ---------------------------------------------------------------------------
__global__ void __launch_bounds__(256, 2) k_main(
    const float* __restrict__ inp, const float* __restrict__ b2p,
    const float* __restrict__ Wp, const float* __restrict__ a1p,
    const float* __restrict__ a2p, const _Float16* __restrict__ v1h,
    const _Float16* __restrict__ w2h, const _Float16* __restrict__ w10h,
    u32* __restrict__ pr)
{
    const int tid  = threadIdx.x;
    const int lane = tid & 63, wv = tid >> 6;
    const int l15  = lane & 15, l4 = lane >> 4;
    const int W    = blockIdx.x * 4 + wv;     // 0..8191
    const int cg   = W & 1, bt = W >> 1;

    // ---- persistent W2 fragments: g = cg*64 + nt*16 + l15, f-window l4 ----
    f16x8 bfr[4][4];
    #pragma unroll
    for (int nt = 0; nt < 4; ++nt)
        #pragma unroll
        for (int kc = 0; kc < 4; ++kc) {
            bfr[nt][kc] = *(const f16x8*)
                &w2h[(cg * 64 + nt * 16 + l15) * 128 + kc * 32 + l4 * 8];
            PIN(bfr[nt][kc]);
        }

    // ---- v1 / w10 lane-windows as packed u32 quads ----
    u32x4 v1q[4], w10q[4];
    #pragma unroll
    for (int kc = 0; kc < 4; ++kc) {
        v1q[kc]  = *(const u32x4*)&v1h[(size_t)bt * 128 + kc * 32 + l4 * 8];
        w10q[kc] = *(const u32x4*)&w10h[kc * 32 + l4 * 8];
        PIN(v1q[kc]); PIN(w10q[kc]);
    }

    // ---- b2 as f32 MFMA C-init + packed Wp slices ----
    f32x4 accInit[4];
    u32 wpapk[4][2], wpbpk[4][2];
    #pragma unroll
    for (int nt = 0; nt < 4; ++nt) {
        const int g0 = cg * 64 + nt * 16 + l4 * 4;
        const float4 bv = *(const float4*)&b2p[g0];
        const float4 wa = *(const float4*)&Wp[g0];
        accInit[nt][0] = bv.x; accInit[nt][1] = bv.y;
        accInit[nt][2] = bv.z; accInit[nt][3] = bv.w;
        wpapk[nt][0] = cvtpk_u(wa.x, wa.y);  wpapk[nt][1] = cvtpk_u(wa.z, wa.w);
        wpbpk[nt][0] = cvtpk_u(Wp[CAT + g0],     Wp[CAT + g0 + 1]);
        wpbpk[nt][1] = cvtpk_u(Wp[CAT + g0 + 2], Wp[CAT + g0 + 3]);
        PIN(accInit[nt]);
        PIN(wpapk[nt][0]); PIN(wpapk[nt][1]);
        PIN(wpbpk[nt][0]); PIN(wpbpk[nt][1]);
    }

    const float a1f = a1p[0], a2f = a2p[0];
    u32 a1pk = cvtpk_u(a1f, a1f);
    u32 a2pk = cvtpk_u(a2f, a2f);
    PIN(a1pk); PIN(a2pk);

    // ---- preload ALL 16 s-values, pre-packed as duplicated f16 ----
    const float* srow = inp + (size_t)bt * DD;
    u32 s2[16];
    #pragma unroll
    for (int i = 0; i < 16; ++i) {
        const float sv = srow[i * 16 + l15];
        s2[i] = cvtpk_u(sv, sv);
        PIN(s2[i]);
    }

    u32* prw = pr + ((size_t)bt * DD) * 2 + cg;

    #pragma unroll
    for (int it = 0; it < 8; ++it) {
        const u32 sA = s2[2 * it], sB = s2[2 * it + 1];

        // ---- packed afr-gen + MFMA (b2 enters as C of first MFMA) ----
        f32x4 accA[4], accB[4];
        #pragma unroll
        for (int kc = 0; kc < 4; ++kc) {
            u32x4 afA, afB;
            #pragma unroll
            for (int j = 0; j < 4; ++j) {
                u32 hA = pk_fma(w10q[kc][j], sA, v1q[kc][j]);
                afA[j] = pk_max(hA, pk_mul(a1pk, hA));
                u32 hB = pk_fma(w10q[kc][j], sB, v1q[kc][j]);
                afB[j] = pk_max(hB, pk_mul(a1pk, hB));
            }
            const f16x8 a8A = __builtin_bit_cast(f16x8, afA);
            const f16x8 a8B = __builtin_bit_cast(f16x8, afB);
            #pragma unroll
            for (int nt = 0; nt < 4; ++nt) {
                accA[nt] = __builtin_amdgcn_mfma_f32_16x16x32_f16(
                    bfr[nt][kc], a8A, (kc == 0) ? accInit[nt] : accA[nt], 0, 0, 0);
                accB[nt] = __builtin_amdgcn_mfma_f32_16x16x32_f16(
                    bfr[nt][kc], a8B, (kc == 0) ? accInit[nt] : accB[nt], 0, 0, 0);
            }
        }

        // ---- packed epilogue; fdot2 chains split for ILP ----
        float p0Aa = 0.f, p0Ab = 0.f, p1Aa = 0.f, p1Ab = 0.f;
        float p0Ba = 0.f, p0Bb = 0.f, p1Ba = 0.f, p1Bb = 0.f;
        #pragma unroll
        for (int nt = 0; nt < 4; ++nt) {
            u32 hA0 = cvtpk_u(accA[nt][0], accA[nt][1]);
            u32 hA1 = cvtpk_u(accA[nt][2], accA[nt][3]);
            u32 pA0 = pk_max(hA0, pk_mul(a2pk, hA0));
            u32 pA1 = pk_max(hA1, pk_mul(a2pk, hA1));
            u32 hB0 = cvtpk_u(accB[nt][0], accB[nt][1]);
            u32 hB1 = cvtpk_u(accB[nt][2], accB[nt][3]);
            u32 pB0 = pk_max(hB0, pk_mul(a2pk, hB0));
            u32 pB1 = pk_max(hB1, pk_mul(a2pk, hB1));
            if (nt < 2) {
                p0Aa = fdot2u(wpapk[nt][0], pA0, p0Aa);
                p0Aa = fdot2u(wpapk[nt][1], pA1, p0Aa);
                p1Aa = fdot2u(wpbpk[nt][0], pA0, p1Aa);
                p1Aa = fdot2u(wpbpk[nt][1], pA1, p1Aa);
                p0Ba = fdot2u(wpapk[nt][0], pB0, p0Ba);
                p0Ba = fdot2u(wpapk[nt][1], pB1, p0Ba);
                p1Ba = fdot2u(wpbpk[nt][0], pB0, p1Ba);
                p1Ba = fdot2u(wpbpk[nt][1], pB1, p1Ba);
            } else {
                p0Ab = fdot2u(wpapk[nt][0], pA0, p0Ab);
                p0Ab = fdot2u(wpapk[nt][1], pA1, p0Ab);
                p1Ab = fdot2u(wpbpk[nt][0], pA0, p1Ab);
                p1Ab = fdot2u(wpbpk[nt][1], pA1, p1Ab);
                p0Bb = fdot2u(wpapk[nt][0], pB0, p0Bb);
                p0Bb = fdot2u(wpapk[nt][1], pB1, p0Bb);
                p1Bb = fdot2u(wpbpk[nt][0], pB0, p1Bb);
                p1Bb = fdot2u(wpbpk[nt][1], pB1, p1Bb);
            }
        }

        float p0A = p0Aa + p0Ab, p1A = p1Aa + p1Ab;
        float p0B = p0Ba + p0Bb, p1B = p1Ba + p1Bb;

        // ---- reduce over l4 (4 lanes, stride 16) ----
        p0A += __shfl_xor(p0A, 16); p0A += __shfl_xor(p0A, 32);
        p1A += __shfl_xor(p1A, 16); p1A += __shfl_xor(p1A, 32);
        p0B += __shfl_xor(p0B, 16); p0B += __shfl_xor(p0B, 32);
        p1B += __shfl_xor(p1B, 16); p1B += __shfl_xor(p1B, 32);

        if (l4 == 0) {
            prw[(it * 32 + l15) * 2]        = cvtpk_u(p0A, p1A);
            prw[(it * 32 + 16 + l15) * 2]   = cvtpk_u(p0B, p1B);
        }
    }
}

// ---------------------------------------------------------------------------
// k_fin: combine 2 cg halves + wpi*s + bp, sigmoid gate, write out. BW-bound.
// ---------------------------------------------------------------------------
__global__ void __launch_bounds__(256) k_fin(
    const float* __restrict__ inp, const float* __restrict__ Wp,
    const float* __restrict__ bpp, const u32* __restrict__ pr,
    float* __restrict__ out)
{
    const int i = blockIdx.x * 256 + threadIdx.x;   // 0 .. BT*DD-1
    const float wpi0 = Wp[128], wpi1 = Wp[CAT + 128];
    const float bp0  = bpp[0],  bp1  = bpp[1];

    const uint2 v = ((const uint2*)pr)[i];
    const h2 pa = __builtin_bit_cast(h2, v.x);   // cg0: (p0, p1)
    const h2 pb = __builtin_bit_cast(h2, v.y);   // cg1: (p0, p1)
    const float s = inp[i];

    const float e0 = (float)pa[0] + (float)pb[0] + wpi0 * s + bp0;
    const float e1 = (float)pa[1] + (float)pb[1] + wpi1 * s + bp1;
    const float gg = e0 / (1.f + __expf(-e1));
    out[i] = s * (1.f + gg);
}

// ---------------------------------------------------------------------------
extern "C" void kernel_launch(void* const* d_in, const int* in_sizes, int n_in,
                              void* d_out, int out_size, void* d_ws, size_t ws_size,
                              hipStream_t stream)
{
    (void)in_sizes; (void)n_in; (void)out_size; (void)ws_size;
    const float* input   = (const float*)d_in[0];
    const float* feature = (const float*)d_in[1];
    // d_in[2] slider: unused by the reference computation
    const float* W1 = (const float*)d_in[3];
    const float* b1 = (const float*)d_in[4];
    const float* a1 = (const float*)d_in[5];
    const float* W2 = (const float*)d_in[6];
    const float* b2 = (const float*)d_in[7];
    const float* a2 = (const float*)d_in[8];
    const float* Wp = (const float*)d_in[9];
    const float* bp = (const float*)d_in[10];
    float* out = (float*)d_out;

    // workspace: pr 8MB | v1h 1MB | w2h 32KB | w1h 32KB | w10h 256B
    u32*       pr   = (u32*)d_ws;
    _Float16*  v1h  = (_Float16*)((char*)d_ws + (size_t)BT * DD * 8);
    _Float16*  w2h  = v1h + (size_t)BT * 128;
    _Float16*  w1h  = w2h + 16384;
    _Float16*  w10h = w1h + 16384;

    k_cvt  <<<dim3(16),   dim3(256), 0, stream>>>(W1, W2, w2h, w1h, w10h);
    k_prep2<<<dim3(256),  dim3(256), 0, stream>>>(feature, w1h, b1, v1h);
    k_main <<<dim3(2048), dim3(256), 0, stream>>>(input, b2, Wp, a1, a2,
                                                  v1h, w2h, w10h, pr);
    k_fin  <<<dim3(4096), dim3(256), 0, stream>>>(input, Wp, bp, pr, out);
}